// Round 3
// baseline (281.133 us; speedup 1.0000x reference)
//
#include <hip/hip_runtime.h>
#include <math.h>
#include <stdint.h>

#pragma clang fp contract(off)

#define BB   4
#define TT   480000
#define DIM  9
#define NTT  3750            // TT / 128

// JAX >= 0.4.30 defaults jax_threefry_partitionable=True (foldlike split,
// per-element (0,i) counters, 32-bit draws = o0^o1). If the bench shows
// absmax ~0.2 (harmonic phases decorrelated => wrong rand_ini), flip to 0
// to get the legacy iota-split PRNG. absmax ~0.03 => noise bits combine
// wrong (try o0 alone instead of o0^o1).
#define PARTITIONABLE 1

// ---------------- Threefry2x32-20 (JAX/Random123) ----------------
__host__ __device__ static inline void threefry2x32(uint32_t k0, uint32_t k1,
                                                    uint32_t x0, uint32_t x1,
                                                    uint32_t& o0, uint32_t& o1) {
  const uint32_t ks2 = k0 ^ k1 ^ 0x1BD11BDAu;
  x0 += k0; x1 += k1;
#define TF_R(r) { x0 += x1; x1 = (x1 << (r)) | (x1 >> (32 - (r))); x1 ^= x0; }
  TF_R(13) TF_R(15) TF_R(26) TF_R(6)
  x0 += k1;  x1 += ks2 + 1u;
  TF_R(17) TF_R(29) TF_R(16) TF_R(24)
  x0 += ks2; x1 += k0 + 2u;
  TF_R(13) TF_R(15) TF_R(26) TF_R(6)
  x0 += k0;  x1 += k1 + 3u;
  TF_R(17) TF_R(29) TF_R(16) TF_R(24)
  x0 += k1;  x1 += ks2 + 4u;
  TF_R(13) TF_R(15) TF_R(26) TF_R(6)
  x0 += ks2; x1 += k0 + 5u;
#undef TF_R
  o0 = x0; o1 = x1;
}

__device__ __forceinline__ float fracf_(float x) { return x - truncf(x); }

__device__ __forceinline__ float u01_(uint32_t bits) {
  return __uint_as_float((bits >> 9) | 0x3f800000u) - 1.0f;
}

// XLA ErfInv32 (Giles poly) — noise path only (ulp-level precision suffices)
__device__ static inline float erfinv_xla(float x) {
  float w = -log1pf(-x * x);
  float p;
  if (w < 5.0f) {
    w = w - 2.5f;
    p = 2.81022636e-08f;
    p = 3.43273939e-07f  + p * w;
    p = -3.5233877e-06f  + p * w;
    p = -4.39150654e-06f + p * w;
    p = 0.00021858087f   + p * w;
    p = -0.00125372503f  + p * w;
    p = -0.00417768164f  + p * w;
    p = 0.246640727f     + p * w;
    p = 1.50140941f      + p * w;
  } else {
    w = sqrtf(w) - 3.0f;
    p = -0.000200214257f;
    p = 0.000100950558f  + p * w;
    p = 0.00134934322f   + p * w;
    p = -0.00367342844f  + p * w;
    p = 0.00573950773f   + p * w;
    p = -0.0076224613f   + p * w;
    p = 0.00943887047f   + p * w;
    p = 1.00167406f      + p * w;
    p = 2.83297682f      + p * w;
  }
  return p * x;
}

// normal sample from raw bits, matching jax.random.normal bit-derivation:
// u = max(lo, u01*2.0f + lo); n = f32(sqrt(2)) * erfinv(u)
__device__ __forceinline__ float nrm_(uint32_t bits) {
  const float LO = -0.9999999403953552f;   // nextafter(-1,0); (hi-lo) rounds to 2.0f
  float u = u01_(bits) * 2.0f + LO;
  u = fmaxf(LO, u);
  return 1.4142135623730951f * erfinv_xla(u);
}

// 32-bit random_bits draw j of a length-n stream (n < 2^32) under key (kk0,kk1)
__device__ __forceinline__ uint32_t ri_bits(uint32_t kk0, uint32_t kk1, uint32_t j) {
  uint32_t o0, o1;
#if PARTITIONABLE
  threefry2x32(kk0, kk1, 0u, j, o0, o1);   // iota_2x32: hi=0, lo=j
  return o0 ^ o1;
#else
  // legacy: iota(36) split in halves, pair (j, j+18)
  if (j < 18u) { threefry2x32(kk0, kk1, j, j + 18u, o0, o1); return o0; }
  threefry2x32(kk0, kk1, j - 18u, j, o0, o1); return o1;
#endif
}

__device__ __forceinline__ uint32_t noise_bits(uint32_t kn0, uint32_t kn1, uint32_t i) {
  uint32_t o0, o1;
#if PARTITIONABLE
  threefry2x32(kn0, kn1, 0u, i, o0, o1);
  return o0 ^ o1;
#else
  const uint32_t half = 2u * TT * DIM;     // 8,640,000
  if (i < half) { threefry2x32(kn0, kn1, i, i + half, o0, o1); return o0; }
  threefry2x32(kn0, kn1, i - half, i, o0, o1); return o1;
#endif
}

// rand_ini[b][k]: uniform(k_ini, (4,9)); fundamental (k==0) forced to 0.
__device__ __forceinline__ float rand_ini_val(uint32_t ki0, uint32_t ki1, int b, int k) {
  if (k == 0) return 0.0f;
  return u01_(ri_bits(ki0, ki1, (uint32_t)(b * DIM + k)));
}

// ---------------- In-wave exact-bracketing scan machinery ----------------
// Wave owns a 128-elem tile; lane l holds elements 2l, 2l+1. Lv[s] at lane i =
// sum of elements [i*2^(s+1), (i+1)*2^(s+1)) with associative_scan pairing.
__device__ __forceinline__ void build_tree(float v1, float Lv[6], int l) {
  Lv[0] = v1;
#pragma unroll
  for (int s = 1; s < 6; ++s)
    Lv[s] = __shfl(Lv[s - 1], 2 * l) + __shfl(Lv[s - 1], 2 * l + 1);
}
__device__ __forceinline__ float tile_sum(const float Lv[6]) {
  return __shfl(Lv[5], 0) + __shfl(Lv[5], 1);
}
// Carry-seeded scan value at in-tile element 2l+1 (prefix n=2l+2), exact
// bracketing: acc=carry (deepest), add set-bit subtree nodes MSB->LSB.
// (l==63 i.e. n=128 is the mid-scan value directly — caller substitutes.)
__device__ __forceinline__ float fold_c1(const float Lv[6], int l, float carry) {
  int n = 2 * l + 2;
  float acc = carry;
#pragma unroll
  for (int b = 6; b >= 1; --b) {
    float t = __shfl(Lv[b - 1], (n >> (b + 1)) << 1);  // ((n>>b)-1) when bit set
    acc = ((n >> b) & 1) ? acc + t : acc;
  }
  return acc;
}

// ---------------- Kernel 1: tile sums (level-7) of rad ----------------
__global__ __launch_bounds__(256) void k_up1(const float* __restrict__ f0,
                                             float* __restrict__ gL7,
                                             uint32_t ki0, uint32_t ki1) {
  int task = blockIdx.x * 4 + (threadIdx.x >> 6);
  int l = threadIdx.x & 63;
  int b = task / NTT, j = task - b * NTT;
  float2 f2 = *(const float2*)(f0 + (size_t)b * TT + j * 128 + 2 * l);
  bool ini = (j == 0) & (l == 0);
#pragma unroll
  for (int k = 0; k < DIM; ++k) {
    float h = (float)(k + 1);
    float r0 = fracf_((f2.x * h) / 48000.0f);
    float r1 = fracf_((f2.y * h) / 48000.0f);
    if (ini) r0 = r0 + rand_ini_val(ki0, ki1, b, k);
    float Lv[6];
    build_tree(r0 + r1, Lv, l);
    float ts = tile_sum(Lv);
    if (l == 0) gL7[(b * DIM + k) * NTT + j] = ts;
  }
}

// ---------------- Kernel 2/4: generic mid-scan (36 rows, n=3750) ----------------
// Implements the associative_scan recursion verbatim (odd sizes included).
__global__ __launch_bounds__(256) void k_midscan(float* __restrict__ gbuf, int NT) {
  __shared__ float buf[7700];
  __shared__ int offs[24], szs[24], nlev;
  int row = blockIdx.x;
  float* g = gbuf + (size_t)row * NT;
  int tid = threadIdx.x, nth = blockDim.x;
  if (tid == 0) {
    int n = NT, off = 0, L = 0;
    for (;;) { offs[L] = off; szs[L] = n; off += n; ++L; if (n == 1) break; n >>= 1; }
    nlev = L;
  }
  __syncthreads();
  int L = nlev;
  for (int i = tid; i < NT; i += nth) buf[i] = g[i];
  __syncthreads();
  for (int l = 0; l + 1 < L; ++l) {                 // up-sweep: pair reduce
    int m = szs[l + 1];
    const float* src = buf + offs[l];
    float* dst = buf + offs[l + 1];
    for (int i = tid; i < m; i += nth) dst[i] = src[2 * i] + src[2 * i + 1];
    __syncthreads();
  }
  for (int l = L - 2; l >= 0; --l) {                // down-sweep (in place)
    int n = szs[l], m = szs[l + 1];
    float* cur = buf + offs[l];
    const float* up = buf + offs[l + 1];
    for (int i = tid; i < m; i += nth) {
      float s = up[i];
      cur[2 * i + 1] = s;
      if (2 * i + 2 < n) cur[2 * i + 2] = s + cur[2 * i + 2];  // odd + elem order
    }
    __syncthreads();
  }
  for (int i = tid; i < NT; i += nth) g[i] = buf[i];
}

// ---------------- Kernel 3: scan1 values -> wrap bits + tile sums of y ----------------
__global__ __launch_bounds__(256) void k_d1u2(const float* __restrict__ f0,
                                              const float* __restrict__ gS71,
                                              float* __restrict__ gL72,
                                              ulonglong2* __restrict__ wrapw,
                                              uint32_t ki0, uint32_t ki1) {
  int task = blockIdx.x * 4 + (threadIdx.x >> 6);
  int l = threadIdx.x & 63;
  int b = task / NTT, j = task - b * NTT;
  float2 f2 = *(const float2*)(f0 + (size_t)b * TT + j * 128 + 2 * l);
  bool ini = (j == 0) & (l == 0);
  bool notfirst = (j > 0) | (l > 0);
#pragma unroll
  for (int k = 0; k < DIM; ++k) {
    float h = (float)(k + 1);
    float r0 = fracf_((f2.x * h) / 48000.0f);
    float r1 = fracf_((f2.y * h) / 48000.0f);
    if (ini) r0 = r0 + rand_ini_val(ki0, ki1, b, k);
    float Lv[6];
    build_tree(r0 + r1, Lv, l);
    int base = (b * DIM + k) * NTT;
    float C  = (j > 0) ? gS71[base + j - 1] : 0.0f;
    float S7 = gS71[base + j];
    float c1 = fold_c1(Lv, l, C);
    c1 = (l == 63) ? S7 : c1;
    float cp = __shfl_up(c1, 1);
    if (l == 0) cp = C;
    float c0 = cp + r0;                  // even position: literally odd_prev + x
    bool w0 = notfirst & (fracf_(c0) < fracf_(cp));
    bool w1 = fracf_(c1) < fracf_(c0);
    float y0 = w0 ? r0 - 1.0f : r0;
    float y1 = w1 ? r1 - 1.0f : r1;
    unsigned long long m0 = __ballot(w0);
    unsigned long long m1 = __ballot(w1);
    float Lw[6];
    build_tree(y0 + y1, Lw, l);
    float ts = tile_sum(Lw);
    if (l == 0) {
      gL72[base + j] = ts;
      wrapw[base + j] = make_ulonglong2(m0, m1);
    }
  }
}

// ---------------- Kernel 5: scan2 -> sin + threefry noise -> out ----------------
__global__ __launch_bounds__(256) void k_d2out(const float* __restrict__ f0,
                                               const float* __restrict__ gS72,
                                               const ulonglong2* __restrict__ wrapw,
                                               float* __restrict__ out,
                                               uint32_t ki0, uint32_t ki1,
                                               uint32_t kn0, uint32_t kn1) {
  int task = blockIdx.x * 4 + (threadIdx.x >> 6);
  int l = threadIdx.x & 63;
  int b = task / NTT, j = task - b * NTT;
  int t0 = j * 128 + 2 * l;
  float2 f2 = *(const float2*)(f0 + (size_t)b * TT + t0);
  bool ini = (j == 0) & (l == 0);
  float uv0 = (f2.x > 0.0f) ? 1.0f : 0.0f;
  float uv1 = (f2.y > 0.0f) ? 1.0f : 0.0f;
  const float AMP3 = 0.0333333333333333333f;   // f32(0.1/3)
  float na0 = uv0 * 0.003f + (1.0f - uv0) * AMP3;
  float na1 = uv1 * 0.003f + (1.0f - uv1) * AMP3;
  const float TWOPI = 6.283185307179586f;      // f32 0x40C90FDB
  float ob[18];
#pragma unroll
  for (int k = 0; k < DIM; ++k) {
    float h = (float)(k + 1);
    float r0 = fracf_((f2.x * h) / 48000.0f);
    float r1 = fracf_((f2.y * h) / 48000.0f);
    if (ini) r0 = r0 + rand_ini_val(ki0, ki1, b, k);
    int base = (b * DIM + k) * NTT;
    ulonglong2 mw = wrapw[base + j];
    float y0 = ((mw.x >> l) & 1ull) ? r0 - 1.0f : r0;
    float y1 = ((mw.y >> l) & 1ull) ? r1 - 1.0f : r1;
    float Lv[6];
    build_tree(y0 + y1, Lv, l);
    float C2 = (j > 0) ? gS72[base + j - 1] : 0.0f;
    float S7 = gS72[base + j];
    float d1 = fold_c1(Lv, l, C2);
    d1 = (l == 63) ? S7 : d1;
    float dp = __shfl_up(d1, 1);
    if (l == 0) dp = C2;
    float d0 = dp + y0;
    float s0 = sinf(TWOPI * d0) * 0.1f;
    float s1 = sinf(TWOPI * d1) * 0.1f;
    uint32_t fi0 = (uint32_t)(b * TT + t0) * (uint32_t)DIM + (uint32_t)k;
    float n0 = nrm_(noise_bits(kn0, kn1, fi0));
    float n1 = nrm_(noise_bits(kn0, kn1, fi0 + (uint32_t)DIM));
    ob[k]       = s0 * uv0 + na0 * n0;
    ob[DIM + k] = s1 * uv1 + na1 * n1;
  }
  float2* p = (float2*)(out + ((size_t)b * TT + t0) * DIM);
#pragma unroll
  for (int s = 0; s < 9; ++s) p[s] = make_float2(ob[2 * s], ob[2 * s + 1]);
}

extern "C" void kernel_launch(void* const* d_in, const int* in_sizes, int n_in,
                              void* d_out, int out_size, void* d_ws, size_t ws_size,
                              hipStream_t stream) {
  (void)in_sizes; (void)n_in; (void)out_size; (void)ws_size;
  const float* f0 = (const float*)d_in[0];
  float* out = (float*)d_out;
  float* gBuf1 = (float*)d_ws;                                   // 36*3750 f32
  float* gBuf2 = gBuf1 + 36 * NTT;                               // 36*3750 f32
  ulonglong2* wrapw =
      (ulonglong2*)((char*)d_ws + (size_t)2 * 36 * NTT * sizeof(float)); // 2.16 MB

  uint32_t ki0, ki1, kn0, kn1;
#if PARTITIONABLE
  // split(key(42)) foldlike: key_i = threefry((0,42), x0=0, x1=i) both words
  threefry2x32(0u, 42u, 0u, 0u, ki0, ki1);   // k_ini
  threefry2x32(0u, 42u, 0u, 1u, kn0, kn1);   // k_noise
#else
  // legacy split: iota(4) halved -> pairs (0,2),(1,3); keys = reshape(concat)
  uint32_t a0, a1, b0, b1;
  threefry2x32(0u, 42u, 0u, 2u, a0, a1);
  threefry2x32(0u, 42u, 1u, 3u, b0, b1);
  ki0 = a0; ki1 = b0;                        // k_ini   = (o0(0,2), o0(1,3))
  kn0 = a1; kn1 = b1;                        // k_noise = (o1(0,2), o1(1,3))
#endif

  k_up1    <<<(BB * NTT) / 4, 256, 0, stream>>>(f0, gBuf1, ki0, ki1);
  k_midscan<<<36, 256, 0, stream>>>(gBuf1, NTT);
  k_d1u2   <<<(BB * NTT) / 4, 256, 0, stream>>>(f0, gBuf1, gBuf2, wrapw, ki0, ki1);
  k_midscan<<<36, 256, 0, stream>>>(gBuf2, NTT);
  k_d2out  <<<(BB * NTT) / 4, 256, 0, stream>>>(f0, gBuf2, wrapw, out,
                                                ki0, ki1, kn0, kn1);
}

// Round 6
// 252.083 us; speedup vs baseline: 1.1152x; 1.1152x over previous
//
#include <hip/hip_runtime.h>
#include <math.h>
#include <stdint.h>

#pragma clang fp contract(off)

#define BB   4
#define TT   480000
#define DIM  9
#define NTT  3750            // TT / 128

#define PARTITIONABLE 1      // confirmed by round-3 pass (absmax 4.9e-4)

// ---------------- Threefry2x32-20 (JAX/Random123) ----------------
__host__ __device__ static inline void threefry2x32(uint32_t k0, uint32_t k1,
                                                    uint32_t x0, uint32_t x1,
                                                    uint32_t& o0, uint32_t& o1) {
  const uint32_t ks2 = k0 ^ k1 ^ 0x1BD11BDAu;
  x0 += k0; x1 += k1;
#define TF_R(r) { x0 += x1; x1 = (x1 << (r)) | (x1 >> (32 - (r))); x1 ^= x0; }
  TF_R(13) TF_R(15) TF_R(26) TF_R(6)
  x0 += k1;  x1 += ks2 + 1u;
  TF_R(17) TF_R(29) TF_R(16) TF_R(24)
  x0 += ks2; x1 += k0 + 2u;
  TF_R(13) TF_R(15) TF_R(26) TF_R(6)
  x0 += k0;  x1 += k1 + 3u;
  TF_R(17) TF_R(29) TF_R(16) TF_R(24)
  x0 += k1;  x1 += ks2 + 4u;
  TF_R(13) TF_R(15) TF_R(26) TF_R(6)
  x0 += ks2; x1 += k0 + 5u;
#undef TF_R
  o0 = x0; o1 = x1;
}

__device__ __forceinline__ float fracf_(float x) { return x - truncf(x); }

__device__ __forceinline__ float u01_(uint32_t bits) {
  return __uint_as_float((bits >> 9) | 0x3f800000u) - 1.0f;
}

// XLA ErfInv32 (Giles poly); log1p(-x^2) -> v_log((1-x)(1+x)) (noise path:
// result is scaled by 0.003, ulp-level differences invisible at 4.9e-4 slack)
__device__ static inline float erfinv_xla(float x) {
  float t = (1.0f - x) * (1.0f + x);                 // > 0 for |x|<1 (guaranteed)
  float w = -0.6931471805599453f * __builtin_amdgcn_logf(t);  // -ln(t)
  float p;
  if (w < 5.0f) {
    w = w - 2.5f;
    p = 2.81022636e-08f;
    p = 3.43273939e-07f  + p * w;
    p = -3.5233877e-06f  + p * w;
    p = -4.39150654e-06f + p * w;
    p = 0.00021858087f   + p * w;
    p = -0.00125372503f  + p * w;
    p = -0.00417768164f  + p * w;
    p = 0.246640727f     + p * w;
    p = 1.50140941f      + p * w;
  } else {
    w = __builtin_amdgcn_sqrtf(w) - 3.0f;
    p = -0.000200214257f;
    p = 0.000100950558f  + p * w;
    p = 0.00134934322f   + p * w;
    p = -0.00367342844f  + p * w;
    p = 0.00573950773f   + p * w;
    p = -0.0076224613f   + p * w;
    p = 0.00943887047f   + p * w;
    p = 1.00167406f      + p * w;
    p = 2.83297682f      + p * w;
  }
  return p * x;
}

__device__ __forceinline__ float nrm_(uint32_t bits) {
  const float LO = -0.9999999403953552f;   // nextafter(-1,0); (hi-lo) -> 2.0f
  float u = u01_(bits) * 2.0f + LO;
  u = fmaxf(LO, u);
  return 1.4142135623730951f * erfinv_xla(u);
}

__device__ __forceinline__ uint32_t ri_bits(uint32_t kk0, uint32_t kk1, uint32_t j) {
  uint32_t o0, o1;
#if PARTITIONABLE
  threefry2x32(kk0, kk1, 0u, j, o0, o1);   // iota_2x32: hi=0, lo=j
  return o0 ^ o1;
#else
  if (j < 18u) { threefry2x32(kk0, kk1, j, j + 18u, o0, o1); return o0; }
  threefry2x32(kk0, kk1, j - 18u, j, o0, o1); return o1;
#endif
}

__device__ __forceinline__ uint32_t noise_bits(uint32_t kn0, uint32_t kn1, uint32_t i) {
  uint32_t o0, o1;
#if PARTITIONABLE
  threefry2x32(kn0, kn1, 0u, i, o0, o1);
  return o0 ^ o1;
#else
  const uint32_t half = 2u * TT * DIM;
  if (i < half) { threefry2x32(kn0, kn1, i, i + half, o0, o1); return o0; }
  threefry2x32(kn0, kn1, i - half, i, o0, o1); return o1;
#endif
}

__device__ __forceinline__ float rand_ini_val(uint32_t ki0, uint32_t ki1, int b, int k) {
  if (k == 0) return 0.0f;
  return u01_(ri_bits(ki0, ki1, (uint32_t)(b * DIM + k)));
}

// ---------------- In-wave exact-bracketing scan machinery ----------------
// Wave owns a 128-elem tile; lane l holds elements 2l, 2l+1. Lv[s] at lane i =
// sum of elements [i*2^(s+1), (i+1)*2^(s+1)) with associative_scan pairing.
__device__ __forceinline__ void build_tree(float v1, float Lv[6], int l) {
  Lv[0] = v1;
#pragma unroll
  for (int s = 1; s < 6; ++s)
    Lv[s] = __shfl(Lv[s - 1], 2 * l) + __shfl(Lv[s - 1], 2 * l + 1);
}
__device__ __forceinline__ float tile_sum(const float Lv[6]) {
  return __shfl(Lv[5], 0) + __shfl(Lv[5], 1);
}
// Carry-seeded scan value at in-tile element 2l+1 (prefix n=2l+2), exact
// bracketing: acc=carry (deepest), add set-bit subtree nodes MSB->LSB.
// (l==63 i.e. n=128 is the mid-scan value directly — caller substitutes.)
__device__ __forceinline__ float fold_c1(const float Lv[6], int l, float carry) {
  int n = 2 * l + 2;
  float acc = carry;
#pragma unroll
  for (int b = 6; b >= 1; --b) {
    float t = __shfl(Lv[b - 1], (n >> (b + 1)) << 1);
    acc = ((n >> b) & 1) ? acc + t : acc;
  }
  return acc;
}

// ---------------- Kernel 1: tile sums (level-7) of rad ----------------
__global__ __launch_bounds__(256) void k_up1(const float* __restrict__ f0,
                                             float* __restrict__ gL7,
                                             uint32_t ki0, uint32_t ki1) {
  int task = blockIdx.x * 4 + (threadIdx.x >> 6);
  int l = threadIdx.x & 63;
  int b = task / NTT, j = task - b * NTT;
  float2 f2 = *(const float2*)(f0 + (size_t)b * TT + j * 128 + 2 * l);
  float rb0 = f2.x / 48000.0f, rb1 = f2.y / 48000.0f;   // correctly-rounded, once
  bool ini = (j == 0) & (l == 0);
#pragma unroll
  for (int k = 0; k < DIM; ++k) {
    float h = (float)(k + 1);
    float r0 = fracf_(rb0 * h);
    float r1 = fracf_(rb1 * h);
    if (ini) r0 = r0 + rand_ini_val(ki0, ki1, b, k);
    float Lv[6];
    build_tree(r0 + r1, Lv, l);
    float ts = tile_sum(Lv);
    if (l == 0) gL7[(b * DIM + k) * NTT + j] = ts;
  }
}

// ---------------- Kernel 2/4: mid-scan, 36 rows, 1 wave/row ----------------
__global__ __launch_bounds__(64) void k_midscan(float* __restrict__ gbuf, int NT) {
  __shared__ float buf[7700];
  int row = blockIdx.x;
  float* g = gbuf + (size_t)row * NT;
  int tid = threadIdx.x, nth = blockDim.x;
  int offs[16], szs[16];
  int L = 0;
  { int n = NT, off = 0;
    for (;;) { offs[L] = off; szs[L] = n; off += n; ++L; if (n == 1) break; n >>= 1; } }
  for (int i = tid; i < NT; i += nth) buf[i] = g[i];
  __syncthreads();
  for (int l = 0; l + 1 < L; ++l) {                 // up-sweep: pair reduce
    int m = szs[l + 1];
    const float* src = buf + offs[l];
    float* dst = buf + offs[l + 1];
    for (int i = tid; i < m; i += nth) dst[i] = src[2 * i] + src[2 * i + 1];
    __syncthreads();
  }
  for (int l = L - 2; l >= 0; --l) {                // down-sweep (in place)
    int n = szs[l], m = szs[l + 1];
    float* cur = buf + offs[l];
    const float* up = buf + offs[l + 1];
    for (int i = tid; i < m; i += nth) {
      float s = up[i];
      cur[2 * i + 1] = s;
      if (2 * i + 2 < n) cur[2 * i + 2] = s + cur[2 * i + 2];  // odd + elem order
    }
    __syncthreads();
  }
  for (int i = tid; i < NT; i += nth) g[i] = buf[i];
}

// ---------------- Kernel 3: scan1 -> wrap bits + tile sums of y ----------------
__global__ __launch_bounds__(256) void k_d1u2(const float* __restrict__ f0,
                                              const float* __restrict__ gS71,
                                              float* __restrict__ gL72,
                                              ulonglong2* __restrict__ wrapw,
                                              uint32_t ki0, uint32_t ki1) {
  int task = blockIdx.x * 4 + (threadIdx.x >> 6);
  int l = threadIdx.x & 63;
  int b = task / NTT, j = task - b * NTT;
  float2 f2 = *(const float2*)(f0 + (size_t)b * TT + j * 128 + 2 * l);
  float rb0 = f2.x / 48000.0f, rb1 = f2.y / 48000.0f;
  bool ini = (j == 0) & (l == 0);
  bool notfirst = (j > 0) | (l > 0);
#pragma unroll
  for (int k = 0; k < DIM; ++k) {
    float h = (float)(k + 1);
    float r0 = fracf_(rb0 * h);
    float r1 = fracf_(rb1 * h);
    if (ini) r0 = r0 + rand_ini_val(ki0, ki1, b, k);
    float Lv[6];
    build_tree(r0 + r1, Lv, l);
    int base = (b * DIM + k) * NTT;
    float C  = (j > 0) ? gS71[base + j - 1] : 0.0f;
    float S7 = gS71[base + j];
    float c1 = fold_c1(Lv, l, C);
    c1 = (l == 63) ? S7 : c1;
    float cp = __shfl_up(c1, 1);
    if (l == 0) cp = C;
    float c0 = cp + r0;                  // even position: literally odd_prev + x
    bool w0 = notfirst & (fracf_(c0) < fracf_(cp));
    bool w1 = fracf_(c1) < fracf_(c0);
    float y0 = w0 ? r0 - 1.0f : r0;
    float y1 = w1 ? r1 - 1.0f : r1;
    unsigned long long m0 = __ballot(w0);
    unsigned long long m1 = __ballot(w1);
    float Lw[6];
    build_tree(y0 + y1, Lw, l);
    float ts = tile_sum(Lw);
    if (l == 0) {
      gL72[base + j] = ts;
      wrapw[base + j] = make_ulonglong2(m0, m1);
    }
  }
}

// ---------------- Kernel 5: scan2 -> v_sin + threefry noise -> out ----------------
__global__ __launch_bounds__(256) void k_d2out(const float* __restrict__ f0,
                                               const float* __restrict__ gS72,
                                               const ulonglong2* __restrict__ wrapw,
                                               float* __restrict__ out,
                                               uint32_t ki0, uint32_t ki1,
                                               uint32_t kn0, uint32_t kn1) {
  int task = blockIdx.x * 4 + (threadIdx.x >> 6);
  int l = threadIdx.x & 63;
  int b = task / NTT, j = task - b * NTT;
  int t0 = j * 128 + 2 * l;
  float2 f2 = *(const float2*)(f0 + (size_t)b * TT + t0);
  float rb0 = f2.x / 48000.0f, rb1 = f2.y / 48000.0f;
  bool ini = (j == 0) & (l == 0);
  float uv0 = (f2.x > 0.0f) ? 1.0f : 0.0f;
  float uv1 = (f2.y > 0.0f) ? 1.0f : 0.0f;
  const float AMP3 = 0.0333333333333333333f;   // f32(0.1/3)
  float na0 = uv0 * 0.003f + (1.0f - uv0) * AMP3;
  float na1 = uv1 * 0.003f + (1.0f - uv1) * AMP3;
  float ob[18];
#pragma unroll
  for (int k = 0; k < DIM; ++k) {
    float h = (float)(k + 1);
    float r0 = fracf_(rb0 * h);
    float r1 = fracf_(rb1 * h);
    if (ini) r0 = r0 + rand_ini_val(ki0, ki1, b, k);
    int base = (b * DIM + k) * NTT;
    ulonglong2 mw = wrapw[base + j];
    float y0 = ((mw.x >> l) & 1ull) ? r0 - 1.0f : r0;
    float y1 = ((mw.y >> l) & 1ull) ? r1 - 1.0f : r1;
    float Lv[6];
    build_tree(y0 + y1, Lv, l);
    float C2 = (j > 0) ? gS72[base + j - 1] : 0.0f;
    float S7 = gS72[base + j];
    float d1 = fold_c1(Lv, l, C2);
    d1 = (l == 63) ? S7 : d1;
    float dp = __shfl_up(d1, 1);
    if (l == 0) dp = C2;
    float d0 = dp + y0;
    // d in (-2,2): v_sin_f32 takes revolutions -> sin(2*pi*d) in one TRANS op
    float s0 = __builtin_amdgcn_sinf(d0) * 0.1f;
    float s1 = __builtin_amdgcn_sinf(d1) * 0.1f;
    uint32_t fi0 = (uint32_t)(b * TT + t0) * (uint32_t)DIM + (uint32_t)k;
    float n0 = nrm_(noise_bits(kn0, kn1, fi0));
    float n1 = nrm_(noise_bits(kn0, kn1, fi0 + (uint32_t)DIM));
    ob[k]       = s0 * uv0 + na0 * n0;
    ob[DIM + k] = s1 * uv1 + na1 * n1;
  }
  float2* p = (float2*)(out + ((size_t)b * TT + t0) * DIM);
#pragma unroll
  for (int s = 0; s < 9; ++s) p[s] = make_float2(ob[2 * s], ob[2 * s + 1]);
}

extern "C" void kernel_launch(void* const* d_in, const int* in_sizes, int n_in,
                              void* d_out, int out_size, void* d_ws, size_t ws_size,
                              hipStream_t stream) {
  (void)in_sizes; (void)n_in; (void)out_size; (void)ws_size;
  const float* f0 = (const float*)d_in[0];
  float* out = (float*)d_out;
  float* gBuf1 = (float*)d_ws;                                   // 36*3750 f32
  float* gBuf2 = gBuf1 + 36 * NTT;                               // 36*3750 f32
  ulonglong2* wrapw =
      (ulonglong2*)((char*)d_ws + (size_t)2 * 36 * NTT * sizeof(float)); // 2.16 MB

  uint32_t ki0, ki1, kn0, kn1;
#if PARTITIONABLE
  threefry2x32(0u, 42u, 0u, 0u, ki0, ki1);   // k_ini   = split(key(42))[0]
  threefry2x32(0u, 42u, 0u, 1u, kn0, kn1);   // k_noise = split(key(42))[1]
#else
  uint32_t a0, a1, b0, b1;
  threefry2x32(0u, 42u, 0u, 2u, a0, a1);
  threefry2x32(0u, 42u, 1u, 3u, b0, b1);
  ki0 = a0; ki1 = b0;
  kn0 = a1; kn1 = b1;
#endif

  k_up1    <<<(BB * NTT) / 4, 256, 0, stream>>>(f0, gBuf1, ki0, ki1);
  k_midscan<<<36, 64, 0, stream>>>(gBuf1, NTT);
  k_d1u2   <<<(BB * NTT) / 4, 256, 0, stream>>>(f0, gBuf1, gBuf2, wrapw, ki0, ki1);
  k_midscan<<<36, 64, 0, stream>>>(gBuf2, NTT);
  k_d2out  <<<(BB * NTT) / 4, 256, 0, stream>>>(f0, gBuf2, wrapw, out,
                                                ki0, ki1, kn0, kn1);
}

// Round 8
// 197.432 us; speedup vs baseline: 1.4239x; 1.2768x over previous
//
#include <hip/hip_runtime.h>
#include <math.h>
#include <stdint.h>

#pragma clang fp contract(off)

#define BB   4
#define TT   480000
#define DIM  9
#define TILE 256
#define NTT  1875            // TT / TILE  (480000 / 256)

#define PARTITIONABLE 1      // confirmed by round-3/6 passes (absmax 4.9e-4)

// ---------------- Threefry2x32-20 (JAX/Random123) ----------------
__host__ __device__ static inline void threefry2x32(uint32_t k0, uint32_t k1,
                                                    uint32_t x0, uint32_t x1,
                                                    uint32_t& o0, uint32_t& o1) {
  const uint32_t ks2 = k0 ^ k1 ^ 0x1BD11BDAu;
  x0 += k0; x1 += k1;
#define TF_R(r) { x0 += x1; x1 = (x1 << (r)) | (x1 >> (32 - (r))); x1 ^= x0; }
  TF_R(13) TF_R(15) TF_R(26) TF_R(6)
  x0 += k1;  x1 += ks2 + 1u;
  TF_R(17) TF_R(29) TF_R(16) TF_R(24)
  x0 += ks2; x1 += k0 + 2u;
  TF_R(13) TF_R(15) TF_R(26) TF_R(6)
  x0 += k0;  x1 += k1 + 3u;
  TF_R(17) TF_R(29) TF_R(16) TF_R(24)
  x0 += k1;  x1 += ks2 + 4u;
  TF_R(13) TF_R(15) TF_R(26) TF_R(6)
  x0 += ks2; x1 += k0 + 5u;
#undef TF_R
  o0 = x0; o1 = x1;
}

__device__ __forceinline__ float fracf_(float x) { return x - truncf(x); }

__device__ __forceinline__ float u01_(uint32_t bits) {
  return __uint_as_float((bits >> 9) | 0x3f800000u) - 1.0f;
}

// XLA ErfInv32 (Giles poly); log1p(-x^2) -> v_log((1-x)(1+x)) (noise path:
// result scaled by 0.003, ulp differences invisible at the 4.9e-4 class)
__device__ static inline float erfinv_xla(float x) {
  float t = (1.0f - x) * (1.0f + x);
  float w = -0.6931471805599453f * __builtin_amdgcn_logf(t);
  float p;
  if (w < 5.0f) {
    w = w - 2.5f;
    p = 2.81022636e-08f;
    p = 3.43273939e-07f  + p * w;
    p = -3.5233877e-06f  + p * w;
    p = -4.39150654e-06f + p * w;
    p = 0.00021858087f   + p * w;
    p = -0.00125372503f  + p * w;
    p = -0.00417768164f  + p * w;
    p = 0.246640727f     + p * w;
    p = 1.50140941f      + p * w;
  } else {
    w = __builtin_amdgcn_sqrtf(w) - 3.0f;
    p = -0.000200214257f;
    p = 0.000100950558f  + p * w;
    p = 0.00134934322f   + p * w;
    p = -0.00367342844f  + p * w;
    p = 0.00573950773f   + p * w;
    p = -0.0076224613f   + p * w;
    p = 0.00943887047f   + p * w;
    p = 1.00167406f      + p * w;
    p = 2.83297682f      + p * w;
  }
  return p * x;
}

__device__ __forceinline__ float nrm_(uint32_t bits) {
  const float LO = -0.9999999403953552f;   // nextafter(-1,0); (hi-lo) -> 2.0f
  float u = u01_(bits) * 2.0f + LO;
  u = fmaxf(LO, u);
  return 1.4142135623730951f * erfinv_xla(u);
}

__device__ __forceinline__ uint32_t ri_bits(uint32_t kk0, uint32_t kk1, uint32_t j) {
  uint32_t o0, o1;
#if PARTITIONABLE
  threefry2x32(kk0, kk1, 0u, j, o0, o1);   // iota_2x32: hi=0, lo=j
  return o0 ^ o1;
#else
  if (j < 18u) { threefry2x32(kk0, kk1, j, j + 18u, o0, o1); return o0; }
  threefry2x32(kk0, kk1, j - 18u, j, o0, o1); return o1;
#endif
}

__device__ __forceinline__ uint32_t noise_bits(uint32_t kn0, uint32_t kn1, uint32_t i) {
  uint32_t o0, o1;
#if PARTITIONABLE
  threefry2x32(kn0, kn1, 0u, i, o0, o1);
  return o0 ^ o1;
#else
  const uint32_t half = 2u * TT * DIM;
  if (i < half) { threefry2x32(kn0, kn1, i, i + half, o0, o1); return o0; }
  threefry2x32(kn0, kn1, i - half, i, o0, o1); return o1;
#endif
}

__device__ __forceinline__ float rand_ini_val(uint32_t ki0, uint32_t ki1, int b, int k) {
  if (k == 0) return 0.0f;
  return u01_(ri_bits(ki0, ki1, (uint32_t)(b * DIM + k)));
}

// ---------------- In-wave exact-bracketing scan, TILE=256 ----------------
// Lane l holds elements 4l..4l+3. Level-1 nodes (2l,2l+1) and level-2 node l
// are in-lane; Mv[s] at lane i = level-(s+2) node i (s=0..5), built with the
// associative_scan pairing (left+right).
struct Tree { float n1a, n1b, Mv[6]; };

__device__ __forceinline__ void build_tree4(float x0, float x1, float x2, float x3,
                                            Tree& T, int l) {
  T.n1a = x0 + x1;
  T.n1b = x2 + x3;
  T.Mv[0] = T.n1a + T.n1b;
#pragma unroll
  for (int s = 1; s < 6; ++s)
    T.Mv[s] = __shfl(T.Mv[s - 1], 2 * l) + __shfl(T.Mv[s - 1], 2 * l + 1);
}
__device__ __forceinline__ float tile_sum4(const Tree& T) {
  return __shfl(T.Mv[5], 0) + __shfl(T.Mv[5], 1);
}
// Carry-seeded scan value for even in-tile prefix n (n=4l+2 or 4l+4):
// acc = carry, then set-bit subtree nodes MSB->LSB (bit1 = own level-1 node).
// n=256 (lane 63's 4l+4) is the mid-scan value directly — caller substitutes.
__device__ __forceinline__ float fold4(const Tree& T, int n, float carry) {
  float acc = carry;
#pragma unroll
  for (int b = 7; b >= 2; --b) {
    float t = __shfl(T.Mv[b - 2], (n >> (b + 1)) << 1);
    acc = ((n >> b) & 1) ? acc + t : acc;
  }
  if (n & 2) acc = acc + T.n1a;
  return acc;
}

// ---------------- Kernel 1: tile sums (level-8) of rad ----------------
__global__ __launch_bounds__(256) void k_up1(const float* __restrict__ f0,
                                             float* __restrict__ gL,
                                             uint32_t ki0, uint32_t ki1) {
  int task = blockIdx.x * 4 + (threadIdx.x >> 6);
  int l = threadIdx.x & 63;
  int b = task / NTT, j = task - b * NTT;
  float4 f4 = *(const float4*)(f0 + (size_t)b * TT + j * TILE + 4 * l);
  const float RINV = 1.0f / 48000.0f;
  float rb0 = f4.x * RINV, rb1 = f4.y * RINV, rb2 = f4.z * RINV, rb3 = f4.w * RINV;
  bool ini = (j == 0) & (l == 0);
#pragma unroll
  for (int k = 0; k < DIM; ++k) {
    float h = (float)(k + 1);
    float r0 = fracf_(rb0 * h), r1 = fracf_(rb1 * h);
    float r2 = fracf_(rb2 * h), r3 = fracf_(rb3 * h);
    if (ini) r0 = r0 + rand_ini_val(ki0, ki1, b, k);
    Tree T; build_tree4(r0, r1, r2, r3, T, l);
    float ts = tile_sum4(T);
    if (l == 0) gL[(b * DIM + k) * NTT + j] = ts;
  }
}

// ---------------- Kernel 2/4: mid-scan over 1875 tile sums, 36 rows ----------
// Verbatim associative_scan recursion (odd sizes included); compile-time
// level tables; register-pipelined global I/O.
__global__ __launch_bounds__(256) void k_midscan(float* __restrict__ gbuf) {
  const int NLEV = 11;
  const int SZ[11]  = {1875, 937, 468, 234, 117, 58, 29, 14, 7, 3, 1};
  const int OFF[11] = {0, 1875, 2812, 3280, 3514, 3631, 3689, 3718, 3732, 3739, 3742};
  __shared__ float buf[3743];
  float* g = gbuf + (size_t)blockIdx.x * NTT;
  int tid = threadIdx.x;
  float tmp[8];
#pragma unroll
  for (int u = 0; u < 8; ++u) { int i = tid + u * 256; tmp[u] = (i < NTT) ? g[i] : 0.0f; }
#pragma unroll
  for (int u = 0; u < 8; ++u) { int i = tid + u * 256; if (i < NTT) buf[i] = tmp[u]; }
  __syncthreads();
#pragma unroll
  for (int lv = 0; lv + 1 < NLEV; ++lv) {            // up-sweep: pair reduce
    int m = SZ[lv + 1];
    const float* src = buf + OFF[lv];
    float* dst = buf + OFF[lv + 1];
    for (int i = tid; i < m; i += 256) dst[i] = src[2 * i] + src[2 * i + 1];
    __syncthreads();
  }
#pragma unroll
  for (int lv = NLEV - 2; lv >= 0; --lv) {           // down-sweep (in place)
    int n = SZ[lv], m = SZ[lv + 1];
    float* cur = buf + OFF[lv];
    const float* up = buf + OFF[lv + 1];
    for (int i = tid; i < m; i += 256) {
      float s = up[i];
      cur[2 * i + 1] = s;
      if (2 * i + 2 < n) cur[2 * i + 2] = s + cur[2 * i + 2];  // odd + elem order
    }
    __syncthreads();
  }
#pragma unroll
  for (int u = 0; u < 8; ++u) { int i = tid + u * 256; if (i < NTT) g[i] = buf[i]; }
}

// ---------------- Kernel 3: scan1 -> wrap bits + tile sums of y ----------------
__global__ __launch_bounds__(256) void k_d1u2(const float* __restrict__ f0,
                                              const float* __restrict__ gS1,
                                              float* __restrict__ gL2,
                                              ulonglong2* __restrict__ wrapw,
                                              uint32_t ki0, uint32_t ki1) {
  int task = blockIdx.x * 4 + (threadIdx.x >> 6);
  int l = threadIdx.x & 63;
  int b = task / NTT, j = task - b * NTT;
  float4 f4 = *(const float4*)(f0 + (size_t)b * TT + j * TILE + 4 * l);
  const float RINV = 1.0f / 48000.0f;
  float rb0 = f4.x * RINV, rb1 = f4.y * RINV, rb2 = f4.z * RINV, rb3 = f4.w * RINV;
  bool ini = (j == 0) & (l == 0);
  bool notfirst = (j > 0) | (l > 0);
#pragma unroll
  for (int k = 0; k < DIM; ++k) {
    float h = (float)(k + 1);
    float r0 = fracf_(rb0 * h), r1 = fracf_(rb1 * h);
    float r2 = fracf_(rb2 * h), r3 = fracf_(rb3 * h);
    if (ini) r0 = r0 + rand_ini_val(ki0, ki1, b, k);
    Tree T; build_tree4(r0, r1, r2, r3, T, l);
    int base = (b * DIM + k) * NTT;
    float C = (j > 0) ? gS1[base + j - 1] : 0.0f;
    float S = gS1[base + j];
    float c3 = fold4(T, 4 * l + 4, C);
    c3 = (l == 63) ? S : c3;
    float c1 = fold4(T, 4 * l + 2, C);
    float cp = __shfl_up(c3, 1);
    if (l == 0) cp = C;
    float c0 = cp + r0;                 // even positions: odd_prev + x (exact)
    float c2 = c1 + r2;
    float fp = fracf_(cp), g0 = fracf_(c0), g1 = fracf_(c1);
    float g2 = fracf_(c2), g3 = fracf_(c3);
    bool w0 = notfirst & (g0 < fp);
    bool w1 = g1 < g0;
    bool w2 = g2 < g1;
    bool w3 = g3 < g2;
    float y0 = w0 ? r0 - 1.0f : r0, y1 = w1 ? r1 - 1.0f : r1;
    float y2 = w2 ? r2 - 1.0f : r2, y3 = w3 ? r3 - 1.0f : r3;
    unsigned long long m0 = __ballot(w0), m1 = __ballot(w1);
    unsigned long long m2 = __ballot(w2), m3 = __ballot(w3);
    Tree Ty; build_tree4(y0, y1, y2, y3, Ty, l);
    float ts = tile_sum4(Ty);
    if (l == 0) {
      gL2[base + j] = ts;
      wrapw[2 * (base + j)]     = make_ulonglong2(m0, m1);
      wrapw[2 * (base + j) + 1] = make_ulonglong2(m2, m3);
    }
  }
}

// ---------------- Kernel 5: scan2 -> v_sin + threefry noise -> out ----------------
__global__ __launch_bounds__(256) void k_d2out(const float* __restrict__ f0,
                                               const float* __restrict__ gS2,
                                               const ulonglong2* __restrict__ wrapw,
                                               float* __restrict__ out,
                                               uint32_t ki0, uint32_t ki1,
                                               uint32_t kn0, uint32_t kn1) {
  int task = blockIdx.x * 4 + (threadIdx.x >> 6);
  int l = threadIdx.x & 63;
  int b = task / NTT, j = task - b * NTT;
  int t0 = j * TILE + 4 * l;
  float4 f4 = *(const float4*)(f0 + (size_t)b * TT + t0);
  const float RINV = 1.0f / 48000.0f;
  float rb0 = f4.x * RINV, rb1 = f4.y * RINV, rb2 = f4.z * RINV, rb3 = f4.w * RINV;
  bool ini = (j == 0) & (l == 0);
  float uv0 = (f4.x > 0.0f) ? 1.0f : 0.0f, uv1 = (f4.y > 0.0f) ? 1.0f : 0.0f;
  float uv2 = (f4.z > 0.0f) ? 1.0f : 0.0f, uv3 = (f4.w > 0.0f) ? 1.0f : 0.0f;
  const float AMP3 = 0.0333333333333333333f;   // f32(0.1/3)
  float na0 = uv0 * 0.003f + (1.0f - uv0) * AMP3;
  float na1 = uv1 * 0.003f + (1.0f - uv1) * AMP3;
  float na2 = uv2 * 0.003f + (1.0f - uv2) * AMP3;
  float na3 = uv3 * 0.003f + (1.0f - uv3) * AMP3;
  float ob[36];
#pragma unroll
  for (int k = 0; k < DIM; ++k) {
    float h = (float)(k + 1);
    float r0 = fracf_(rb0 * h), r1 = fracf_(rb1 * h);
    float r2 = fracf_(rb2 * h), r3 = fracf_(rb3 * h);
    if (ini) r0 = r0 + rand_ini_val(ki0, ki1, b, k);
    int base = (b * DIM + k) * NTT;
    ulonglong2 wA = wrapw[2 * (base + j)];
    ulonglong2 wB = wrapw[2 * (base + j) + 1];
    float y0 = ((wA.x >> l) & 1ull) ? r0 - 1.0f : r0;
    float y1 = ((wA.y >> l) & 1ull) ? r1 - 1.0f : r1;
    float y2 = ((wB.x >> l) & 1ull) ? r2 - 1.0f : r2;
    float y3 = ((wB.y >> l) & 1ull) ? r3 - 1.0f : r3;
    Tree T; build_tree4(y0, y1, y2, y3, T, l);
    float C2 = (j > 0) ? gS2[base + j - 1] : 0.0f;
    float S2 = gS2[base + j];
    float d3 = fold4(T, 4 * l + 4, C2);
    d3 = (l == 63) ? S2 : d3;
    float d1 = fold4(T, 4 * l + 2, C2);
    float dp = __shfl_up(d3, 1);
    if (l == 0) dp = C2;
    float d0 = dp + y0;
    float d2 = d1 + y2;
    // d in (-2,2): v_sin_f32 takes revolutions -> sin(2*pi*d) in one TRANS op
    float s0 = __builtin_amdgcn_sinf(d0) * 0.1f;
    float s1 = __builtin_amdgcn_sinf(d1) * 0.1f;
    float s2 = __builtin_amdgcn_sinf(d2) * 0.1f;
    float s3 = __builtin_amdgcn_sinf(d3) * 0.1f;
    uint32_t fi = (uint32_t)(b * TT + t0) * (uint32_t)DIM + (uint32_t)k;
    float n0 = nrm_(noise_bits(kn0, kn1, fi));
    float n1 = nrm_(noise_bits(kn0, kn1, fi + 9u));
    float n2 = nrm_(noise_bits(kn0, kn1, fi + 18u));
    float n3 = nrm_(noise_bits(kn0, kn1, fi + 27u));
    ob[k]      = s0 * uv0 + na0 * n0;
    ob[9 + k]  = s1 * uv1 + na1 * n1;
    ob[18 + k] = s2 * uv2 + na2 * n2;
    ob[27 + k] = s3 * uv3 + na3 * n3;
  }
  // lane owns 36 contiguous output floats, 16B-aligned -> 9 aligned float4s
  float4* po = (float4*)(out + ((size_t)b * TT + t0) * DIM);
#pragma unroll
  for (int q = 0; q < 9; ++q)
    po[q] = make_float4(ob[4 * q], ob[4 * q + 1], ob[4 * q + 2], ob[4 * q + 3]);
}

extern "C" void kernel_launch(void* const* d_in, const int* in_sizes, int n_in,
                              void* d_out, int out_size, void* d_ws, size_t ws_size,
                              hipStream_t stream) {
  (void)in_sizes; (void)n_in; (void)out_size; (void)ws_size;
  const float* f0 = (const float*)d_in[0];
  float* out = (float*)d_out;
  float* gBuf1 = (float*)d_ws;                                   // 36*1875 f32
  float* gBuf2 = gBuf1 + 36 * NTT;                               // 36*1875 f32
  ulonglong2* wrapw =
      (ulonglong2*)((char*)d_ws + (size_t)2 * 36 * NTT * sizeof(float)); // 2.16 MB

  uint32_t ki0, ki1, kn0, kn1;
#if PARTITIONABLE
  threefry2x32(0u, 42u, 0u, 0u, ki0, ki1);   // k_ini   = split(key(42))[0]
  threefry2x32(0u, 42u, 0u, 1u, kn0, kn1);   // k_noise = split(key(42))[1]
#else
  uint32_t a0, a1, b0, b1;
  threefry2x32(0u, 42u, 0u, 2u, a0, a1);
  threefry2x32(0u, 42u, 1u, 3u, b0, b1);
  ki0 = a0; ki1 = b0;
  kn0 = a1; kn1 = b1;
#endif

  k_up1    <<<(BB * NTT) / 4, 256, 0, stream>>>(f0, gBuf1, ki0, ki1);
  k_midscan<<<36, 256, 0, stream>>>(gBuf1);
  k_d1u2   <<<(BB * NTT) / 4, 256, 0, stream>>>(f0, gBuf1, gBuf2, wrapw, ki0, ki1);
  k_midscan<<<36, 256, 0, stream>>>(gBuf2);
  k_d2out  <<<(BB * NTT) / 4, 256, 0, stream>>>(f0, gBuf2, wrapw, out,
                                                ki0, ki1, kn0, kn1);
}

// Round 9
// 179.319 us; speedup vs baseline: 1.5678x; 1.1010x over previous
//
#include <hip/hip_runtime.h>
#include <math.h>
#include <stdint.h>

#pragma clang fp contract(off)

#define BB   4
#define TT   480000
#define DIM  9
#define TILE 256
#define NTT  1875            // TT / TILE

#define PARTITIONABLE 1      // confirmed round-3/6/8 (absmax 4.9e-4)

// ---------------- Threefry2x32-20 (JAX/Random123) ----------------
__host__ __device__ static inline void threefry2x32(uint32_t k0, uint32_t k1,
                                                    uint32_t x0, uint32_t x1,
                                                    uint32_t& o0, uint32_t& o1) {
  const uint32_t ks2 = k0 ^ k1 ^ 0x1BD11BDAu;
  x0 += k0; x1 += k1;
#define TF_R(r) { x0 += x1; x1 = (x1 << (r)) | (x1 >> (32 - (r))); x1 ^= x0; }
  TF_R(13) TF_R(15) TF_R(26) TF_R(6)
  x0 += k1;  x1 += ks2 + 1u;
  TF_R(17) TF_R(29) TF_R(16) TF_R(24)
  x0 += ks2; x1 += k0 + 2u;
  TF_R(13) TF_R(15) TF_R(26) TF_R(6)
  x0 += k0;  x1 += k1 + 3u;
  TF_R(17) TF_R(29) TF_R(16) TF_R(24)
  x0 += k1;  x1 += ks2 + 4u;
  TF_R(13) TF_R(15) TF_R(26) TF_R(6)
  x0 += ks2; x1 += k0 + 5u;
#undef TF_R
  o0 = x0; o1 = x1;
}

__device__ __forceinline__ float fracf_(float x) { return x - truncf(x); }

__device__ __forceinline__ float u01_(uint32_t bits) {
  return __uint_as_float((bits >> 9) | 0x3f800000u) - 1.0f;
}

// XLA ErfInv32 (Giles poly); noise path only (0.003-scaled, ulp-insensitive)
__device__ static inline float erfinv_xla(float x) {
  float t = (1.0f - x) * (1.0f + x);
  float w = -0.6931471805599453f * __builtin_amdgcn_logf(t);
  float p;
  if (w < 5.0f) {
    w = w - 2.5f;
    p = 2.81022636e-08f;
    p = 3.43273939e-07f  + p * w;
    p = -3.5233877e-06f  + p * w;
    p = -4.39150654e-06f + p * w;
    p = 0.00021858087f   + p * w;
    p = -0.00125372503f  + p * w;
    p = -0.00417768164f  + p * w;
    p = 0.246640727f     + p * w;
    p = 1.50140941f      + p * w;
  } else {
    w = __builtin_amdgcn_sqrtf(w) - 3.0f;
    p = -0.000200214257f;
    p = 0.000100950558f  + p * w;
    p = 0.00134934322f   + p * w;
    p = -0.00367342844f  + p * w;
    p = 0.00573950773f   + p * w;
    p = -0.0076224613f   + p * w;
    p = 0.00943887047f   + p * w;
    p = 1.00167406f      + p * w;
    p = 2.83297682f      + p * w;
  }
  return p * x;
}

__device__ __forceinline__ float nrm_(uint32_t bits) {
  const float LO = -0.9999999403953552f;   // nextafter(-1,0); (hi-lo) -> 2.0f
  float u = u01_(bits) * 2.0f + LO;
  u = fmaxf(LO, u);
  return 1.4142135623730951f * erfinv_xla(u);
}

__device__ __forceinline__ uint32_t ri_bits(uint32_t kk0, uint32_t kk1, uint32_t j) {
  uint32_t o0, o1;
#if PARTITIONABLE
  threefry2x32(kk0, kk1, 0u, j, o0, o1);   // iota_2x32: hi=0, lo=j
  return o0 ^ o1;
#else
  if (j < 18u) { threefry2x32(kk0, kk1, j, j + 18u, o0, o1); return o0; }
  threefry2x32(kk0, kk1, j - 18u, j, o0, o1); return o1;
#endif
}

__device__ __forceinline__ uint32_t noise_bits(uint32_t kn0, uint32_t kn1, uint32_t i) {
  uint32_t o0, o1;
#if PARTITIONABLE
  threefry2x32(kn0, kn1, 0u, i, o0, o1);
  return o0 ^ o1;
#else
  const uint32_t half = 2u * TT * DIM;
  if (i < half) { threefry2x32(kn0, kn1, i, i + half, o0, o1); return o0; }
  threefry2x32(kn0, kn1, i - half, i, o0, o1); return o1;
#endif
}

__device__ __forceinline__ float rand_ini_val(uint32_t ki0, uint32_t ki1, int b, int k) {
  if (k == 0) return 0.0f;
  return u01_(ri_bits(ki0, ki1, (uint32_t)(b * DIM + k)));
}

// y = mask[lane] ? bTrue : aFalse  -- one v_cndmask_b32 with SGPR-pair predicate
__device__ __forceinline__ float selbit(unsigned long long m, float aFalse, float bTrue) {
  float r;
  asm("v_cndmask_b32 %0, %1, %2, %3" : "=v"(r) : "v"(aFalse), "v"(bTrue), "s"(m));
  return r;
}

// ---------------- In-wave exact-bracketing scan, TILE=256 ----------------
// Lane l holds elements 4l..4l+3. Level-1 nodes and level-2 node in-lane;
// Mv[s] at lane i = level-(s+2) node i, associative_scan pairing.
struct Tree { float n1a, n1b, Mv[6]; };

__device__ __forceinline__ void build_tree4(float x0, float x1, float x2, float x3,
                                            Tree& T, int l) {
  T.n1a = x0 + x1;
  T.n1b = x2 + x3;
  T.Mv[0] = T.n1a + T.n1b;
#pragma unroll
  for (int s = 1; s < 6; ++s)
    T.Mv[s] = __shfl(T.Mv[s - 1], 2 * l) + __shfl(T.Mv[s - 1], 2 * l + 1);
}
__device__ __forceinline__ float tile_sum4(const Tree& T) {
  return __shfl(T.Mv[5], 0) + __shfl(T.Mv[5], 1);
}
// Carry-seeded scan value for even in-tile prefix n (4l+2 / 4l+4); n=256 is
// the mid-scan value directly (caller substitutes).
__device__ __forceinline__ float fold4(const Tree& T, int n, float carry) {
  float acc = carry;
#pragma unroll
  for (int b = 7; b >= 2; --b) {
    float t = __shfl(T.Mv[b - 2], (n >> (b + 1)) << 1);
    acc = ((n >> b) & 1) ? acc + t : acc;
  }
  if (n & 2) acc = acc + T.n1a;
  return acc;
}

// ---------------- Kernel 1: tile sums (level-8) of rad ----------------
__global__ __launch_bounds__(256) void k_up1(const float* __restrict__ f0,
                                             float* __restrict__ gL,
                                             uint32_t ki0, uint32_t ki1) {
  int task = blockIdx.x * 4 + (threadIdx.x >> 6);
  int l = threadIdx.x & 63;
  int b = task / NTT, j = task - b * NTT;
  float4 f4 = *(const float4*)(f0 + (size_t)b * TT + j * TILE + 4 * l);
  const float RINV = 1.0f / 48000.0f;
  float rb0 = f4.x * RINV, rb1 = f4.y * RINV, rb2 = f4.z * RINV, rb3 = f4.w * RINV;
  bool ini = (j == 0) & (l == 0);
#pragma unroll
  for (int k = 0; k < DIM; ++k) {
    float h = (float)(k + 1);
    float r0 = fracf_(rb0 * h), r1 = fracf_(rb1 * h);
    float r2 = fracf_(rb2 * h), r3 = fracf_(rb3 * h);
    if (ini) r0 = r0 + rand_ini_val(ki0, ki1, b, k);
    Tree T; build_tree4(r0, r1, r2, r3, T, l);
    float ts = tile_sum4(T);
    if (l == 0) gL[(b * DIM + k) * NTT + j] = ts;
  }
}

// ---------------- Kernel 2/4: mid-scan, ONE WAVE PER ROW, no barriers ------
// 36 rows / 4 waves per block = 9 blocks. Wave-private LDS slices; within-wave
// LDS ordering is guaranteed by compiler-inserted lgkmcnt waits.
__global__ __launch_bounds__(256) void k_midscan(float* __restrict__ gbuf) {
  const int NLEV = 11;
  const int SZ[11]  = {1875, 937, 468, 234, 117, 58, 29, 14, 7, 3, 1};
  const int OFF[11] = {0, 1875, 2812, 3280, 3514, 3631, 3689, 3718, 3732, 3739, 3742};
  __shared__ float buf[4][3743];               // 59,888 B
  int w = threadIdx.x >> 6, l = threadIdx.x & 63;
  int row = blockIdx.x * 4 + w;
  float* g = gbuf + (size_t)row * NTT;
  float* s = buf[w];
  for (int i = l; i < NTT; i += 64) s[i] = g[i];
#pragma unroll
  for (int lv = 0; lv + 1 < NLEV; ++lv) {      // up-sweep: pair reduce
    int m = SZ[lv + 1];
    const float* src = s + OFF[lv];
    float* dst = s + OFF[lv + 1];
    for (int i = l; i < m; i += 64) dst[i] = src[2 * i] + src[2 * i + 1];
  }
#pragma unroll
  for (int lv = NLEV - 2; lv >= 0; --lv) {     // down-sweep (in place)
    int n = SZ[lv], m = SZ[lv + 1];
    float* cur = s + OFF[lv];
    const float* up = s + OFF[lv + 1];
    for (int i = l; i < m; i += 64) {
      float ss = up[i];
      cur[2 * i + 1] = ss;
      if (2 * i + 2 < n) cur[2 * i + 2] = ss + cur[2 * i + 2];
    }
  }
  for (int i = l; i < NTT; i += 64) g[i] = s[i];
}

// ---------------- Kernel 3: scan1 -> wrap bits + tile sums of y ------------
__global__ __launch_bounds__(256) void k_d1u2(const float* __restrict__ f0,
                                              const float* __restrict__ gS1,
                                              float* __restrict__ gL2,
                                              ulonglong2* __restrict__ wrapw,
                                              uint32_t ki0, uint32_t ki1) {
  int task = blockIdx.x * 4 + (threadIdx.x >> 6);
  int l = threadIdx.x & 63;
  int b = task / NTT, j = task - b * NTT;
  float4 f4 = *(const float4*)(f0 + (size_t)b * TT + j * TILE + 4 * l);
  const float RINV = 1.0f / 48000.0f;
  float rb0 = f4.x * RINV, rb1 = f4.y * RINV, rb2 = f4.z * RINV, rb3 = f4.w * RINV;
  bool ini = (j == 0) & (l == 0);
  bool notfirst = (j > 0) | (l > 0);
#pragma unroll
  for (int k = 0; k < DIM; ++k) {
    float h = (float)(k + 1);
    float r0 = fracf_(rb0 * h), r1 = fracf_(rb1 * h);
    float r2 = fracf_(rb2 * h), r3 = fracf_(rb3 * h);
    if (ini) r0 = r0 + rand_ini_val(ki0, ki1, b, k);
    Tree T; build_tree4(r0, r1, r2, r3, T, l);
    int bju = __builtin_amdgcn_readfirstlane((b * DIM + k) * NTT + j);
    float S = gS1[bju];                        // scalar loads (uniform index)
    float C = (j > 0) ? gS1[bju - 1] : 0.0f;
    float c3 = fold4(T, 4 * l + 4, C);
    c3 = (l == 63) ? S : c3;
    float c1 = fold4(T, 4 * l + 2, C);
    float cp = __shfl_up(c3, 1);
    if (l == 0) cp = C;
    float c0 = cp + r0;                        // even positions: odd_prev + x
    float c2 = c1 + r2;
    float fp = fracf_(cp), g0 = fracf_(c0), g1 = fracf_(c1);
    float g2 = fracf_(c2), g3 = fracf_(c3);
    bool w0 = notfirst & (g0 < fp);
    bool w1 = g1 < g0;
    bool w2 = g2 < g1;
    bool w3 = g3 < g2;
    float y0 = w0 ? r0 - 1.0f : r0, y1 = w1 ? r1 - 1.0f : r1;
    float y2 = w2 ? r2 - 1.0f : r2, y3 = w3 ? r3 - 1.0f : r3;
    unsigned long long m0 = __ballot(w0), m1 = __ballot(w1);
    unsigned long long m2 = __ballot(w2), m3 = __ballot(w3);
    Tree Ty; build_tree4(y0, y1, y2, y3, Ty, l);
    float ts = tile_sum4(Ty);
    if (l == 0) {
      gL2[bju] = ts;
      wrapw[2 * (size_t)bju]     = make_ulonglong2(m0, m1);
      wrapw[2 * (size_t)bju + 1] = make_ulonglong2(m2, m3);
    }
  }
}

// ---------------- Kernel 5: scan2 -> v_sin + threefry noise -> out ---------
__global__ __launch_bounds__(256) void k_d2out(const float* __restrict__ f0,
                                               const float* __restrict__ gS2,
                                               const ulonglong2* __restrict__ wrapw,
                                               float* __restrict__ out,
                                               uint32_t ki0, uint32_t ki1,
                                               uint32_t kn0, uint32_t kn1) {
  __shared__ float sb[4][64 * 37];             // 37,888 B; stride 37 -> no conflicts
  int w = threadIdx.x >> 6, l = threadIdx.x & 63;
  int task = blockIdx.x * 4 + w;
  int b = task / NTT, j = task - b * NTT;
  int t0 = j * TILE + 4 * l;
  float4 f4 = *(const float4*)(f0 + (size_t)b * TT + t0);
  const float RINV = 1.0f / 48000.0f;
  float rb0 = f4.x * RINV, rb1 = f4.y * RINV, rb2 = f4.z * RINV, rb3 = f4.w * RINV;
  bool ini = (j == 0) & (l == 0);
  float uv0 = (f4.x > 0.0f) ? 1.0f : 0.0f, uv1 = (f4.y > 0.0f) ? 1.0f : 0.0f;
  float uv2 = (f4.z > 0.0f) ? 1.0f : 0.0f, uv3 = (f4.w > 0.0f) ? 1.0f : 0.0f;
  const float AMP3 = 0.0333333333333333333f;   // f32(0.1/3)
  float na0 = uv0 * 0.003f + (1.0f - uv0) * AMP3;
  float na1 = uv1 * 0.003f + (1.0f - uv1) * AMP3;
  float na2 = uv2 * 0.003f + (1.0f - uv2) * AMP3;
  float na3 = uv3 * 0.003f + (1.0f - uv3) * AMP3;
  float* sl = sb[w];
  int sbase = l * 37;
#pragma unroll
  for (int k = 0; k < DIM; ++k) {
    float h = (float)(k + 1);
    float r0 = fracf_(rb0 * h), r1 = fracf_(rb1 * h);
    float r2 = fracf_(rb2 * h), r3 = fracf_(rb3 * h);
    if (ini) r0 = r0 + rand_ini_val(ki0, ki1, b, k);
    int bju = __builtin_amdgcn_readfirstlane((b * DIM + k) * NTT + j);
    // scalar loads: wrap masks (32B) + carries (8B)
    ulonglong2 wA = wrapw[2 * (size_t)bju];
    ulonglong2 wB = wrapw[2 * (size_t)bju + 1];
    float S2 = gS2[bju];
    float C2 = (j > 0) ? gS2[bju - 1] : 0.0f;
    float y0 = selbit(wA.x, r0, r0 - 1.0f);
    float y1 = selbit(wA.y, r1, r1 - 1.0f);
    float y2 = selbit(wB.x, r2, r2 - 1.0f);
    float y3 = selbit(wB.y, r3, r3 - 1.0f);
    Tree T; build_tree4(y0, y1, y2, y3, T, l);
    float d3 = fold4(T, 4 * l + 4, C2);
    d3 = (l == 63) ? S2 : d3;
    float d1 = fold4(T, 4 * l + 2, C2);
    float dp = __shfl_up(d3, 1);
    if (l == 0) dp = C2;
    float d0 = dp + y0;
    float d2 = d1 + y2;
    // d in (-2,2): v_sin_f32 takes revolutions -> sin(2*pi*d) in one TRANS op
    float s0 = __builtin_amdgcn_sinf(d0) * 0.1f;
    float s1 = __builtin_amdgcn_sinf(d1) * 0.1f;
    float s2 = __builtin_amdgcn_sinf(d2) * 0.1f;
    float s3 = __builtin_amdgcn_sinf(d3) * 0.1f;
    uint32_t fi = (uint32_t)(b * TT + t0) * (uint32_t)DIM + (uint32_t)k;
    float n0 = nrm_(noise_bits(kn0, kn1, fi));
    float n1 = nrm_(noise_bits(kn0, kn1, fi + 9u));
    float n2 = nrm_(noise_bits(kn0, kn1, fi + 18u));
    float n3 = nrm_(noise_bits(kn0, kn1, fi + 27u));
    sl[sbase + k]      = s0 * uv0 + na0 * n0;  // lds[37*l + 9*i + k]
    sl[sbase + 9 + k]  = s1 * uv1 + na1 * n1;
    sl[sbase + 18 + k] = s2 * uv2 + na2 * n2;
    sl[sbase + 27 + k] = s3 * uv3 + na3 * n3;
  }
  // Same-wave dump (no barrier): lane reads addr = e + e/36, writes coalesced
  // 1KB wave-stores. e = (q*64+l)*4 stays within one 36-float block (4|36).
  float4* po = (float4*)(out + ((size_t)b * TT + (size_t)j * TILE) * DIM);
#pragma unroll
  for (int q = 0; q < 9; ++q) {
    int gg = (q * 64 + l) * 4;
    int a = gg + gg / 36;
    float4 v = make_float4(sl[a], sl[a + 1], sl[a + 2], sl[a + 3]);
    po[q * 64 + l] = v;
  }
}

extern "C" void kernel_launch(void* const* d_in, const int* in_sizes, int n_in,
                              void* d_out, int out_size, void* d_ws, size_t ws_size,
                              hipStream_t stream) {
  (void)in_sizes; (void)n_in; (void)out_size; (void)ws_size;
  const float* f0 = (const float*)d_in[0];
  float* out = (float*)d_out;
  float* gBuf1 = (float*)d_ws;                                   // 36*1875 f32
  float* gBuf2 = gBuf1 + 36 * NTT;                               // 36*1875 f32
  ulonglong2* wrapw =
      (ulonglong2*)((char*)d_ws + (size_t)2 * 36 * NTT * sizeof(float)); // 2.16 MB

  uint32_t ki0, ki1, kn0, kn1;
#if PARTITIONABLE
  threefry2x32(0u, 42u, 0u, 0u, ki0, ki1);   // k_ini   = split(key(42))[0]
  threefry2x32(0u, 42u, 0u, 1u, kn0, kn1);   // k_noise = split(key(42))[1]
#else
  uint32_t a0, a1, b0, b1;
  threefry2x32(0u, 42u, 0u, 2u, a0, a1);
  threefry2x32(0u, 42u, 1u, 3u, b0, b1);
  ki0 = a0; ki1 = b0;
  kn0 = a1; kn1 = b1;
#endif

  k_up1    <<<(BB * NTT) / 4, 256, 0, stream>>>(f0, gBuf1, ki0, ki1);
  k_midscan<<<9, 256, 0, stream>>>(gBuf1);
  k_d1u2   <<<(BB * NTT) / 4, 256, 0, stream>>>(f0, gBuf1, gBuf2, wrapw, ki0, ki1);
  k_midscan<<<9, 256, 0, stream>>>(gBuf2);
  k_d2out  <<<(BB * NTT) / 4, 256, 0, stream>>>(f0, gBuf2, wrapw, out,
                                                ki0, ki1, kn0, kn1);
}

// Round 10
// 173.441 us; speedup vs baseline: 1.6209x; 1.0339x over previous
//
#include <hip/hip_runtime.h>
#include <math.h>
#include <stdint.h>

#pragma clang fp contract(off)

#define BB   4
#define TT   480000
#define DIM  9
#define TILE 256
#define NTT  1875            // TT / TILE

#define PARTITIONABLE 1      // confirmed round-3/6/8/9 (absmax 4.9e-4)

// ---------------- Threefry2x32-20 (JAX/Random123) ----------------
__host__ __device__ static inline void threefry2x32(uint32_t k0, uint32_t k1,
                                                    uint32_t x0, uint32_t x1,
                                                    uint32_t& o0, uint32_t& o1) {
  const uint32_t ks2 = k0 ^ k1 ^ 0x1BD11BDAu;
  x0 += k0; x1 += k1;
#define TF_R(r) { x0 += x1; x1 = (x1 << (r)) | (x1 >> (32 - (r))); x1 ^= x0; }
  TF_R(13) TF_R(15) TF_R(26) TF_R(6)
  x0 += k1;  x1 += ks2 + 1u;
  TF_R(17) TF_R(29) TF_R(16) TF_R(24)
  x0 += ks2; x1 += k0 + 2u;
  TF_R(13) TF_R(15) TF_R(26) TF_R(6)
  x0 += k0;  x1 += k1 + 3u;
  TF_R(17) TF_R(29) TF_R(16) TF_R(24)
  x0 += k1;  x1 += ks2 + 4u;
  TF_R(13) TF_R(15) TF_R(26) TF_R(6)
  x0 += ks2; x1 += k0 + 5u;
#undef TF_R
  o0 = x0; o1 = x1;
}

__device__ __forceinline__ float fracf_(float x) { return x - truncf(x); }

__device__ __forceinline__ float u01_(uint32_t bits) {
  return __uint_as_float((bits >> 9) | 0x3f800000u) - 1.0f;
}

// XLA ErfInv32 (Giles poly); noise path only (0.003-scaled, ulp-insensitive)
__device__ static inline float erfinv_xla(float x) {
  float t = (1.0f - x) * (1.0f + x);
  float w = -0.6931471805599453f * __builtin_amdgcn_logf(t);
  float p;
  if (w < 5.0f) {
    w = w - 2.5f;
    p = 2.81022636e-08f;
    p = 3.43273939e-07f  + p * w;
    p = -3.5233877e-06f  + p * w;
    p = -4.39150654e-06f + p * w;
    p = 0.00021858087f   + p * w;
    p = -0.00125372503f  + p * w;
    p = -0.00417768164f  + p * w;
    p = 0.246640727f     + p * w;
    p = 1.50140941f      + p * w;
  } else {
    w = __builtin_amdgcn_sqrtf(w) - 3.0f;
    p = -0.000200214257f;
    p = 0.000100950558f  + p * w;
    p = 0.00134934322f   + p * w;
    p = -0.00367342844f  + p * w;
    p = 0.00573950773f   + p * w;
    p = -0.0076224613f   + p * w;
    p = 0.00943887047f   + p * w;
    p = 1.00167406f      + p * w;
    p = 2.83297682f      + p * w;
  }
  return p * x;
}

__device__ __forceinline__ float nrm_(uint32_t bits) {
  const float LO = -0.9999999403953552f;   // nextafter(-1,0); (hi-lo) -> 2.0f
  float u = u01_(bits) * 2.0f + LO;
  u = fmaxf(LO, u);
  return 1.4142135623730951f * erfinv_xla(u);
}

__device__ __forceinline__ uint32_t ri_bits(uint32_t kk0, uint32_t kk1, uint32_t j) {
  uint32_t o0, o1;
#if PARTITIONABLE
  threefry2x32(kk0, kk1, 0u, j, o0, o1);   // iota_2x32: hi=0, lo=j
  return o0 ^ o1;
#else
  if (j < 18u) { threefry2x32(kk0, kk1, j, j + 18u, o0, o1); return o0; }
  threefry2x32(kk0, kk1, j - 18u, j, o0, o1); return o1;
#endif
}

__device__ __forceinline__ uint32_t noise_bits(uint32_t kn0, uint32_t kn1, uint32_t i) {
  uint32_t o0, o1;
#if PARTITIONABLE
  threefry2x32(kn0, kn1, 0u, i, o0, o1);
  return o0 ^ o1;
#else
  const uint32_t half = 2u * TT * DIM;
  if (i < half) { threefry2x32(kn0, kn1, i, i + half, o0, o1); return o0; }
  threefry2x32(kn0, kn1, i - half, i, o0, o1); return o1;
#endif
}

__device__ __forceinline__ float rand_ini_val(uint32_t ki0, uint32_t ki1, int b, int k) {
  if (k == 0) return 0.0f;
  return u01_(ri_bits(ki0, ki1, (uint32_t)(b * DIM + k)));
}

// y = mask[lane] ? bTrue : aFalse  -- one v_cndmask_b32 with SGPR-pair predicate
__device__ __forceinline__ float selbit(unsigned long long m, float aFalse, float bTrue) {
  float r;
  asm("v_cndmask_b32 %0, %1, %2, %3" : "=v"(r) : "v"(aFalse), "v"(bTrue), "s"(m));
  return r;
}

// ---------------- In-wave exact-bracketing scan, TILE=256 ----------------
struct Tree { float n1a, n1b, Mv[6]; };

__device__ __forceinline__ void build_tree4(float x0, float x1, float x2, float x3,
                                            Tree& T, int l) {
  T.n1a = x0 + x1;
  T.n1b = x2 + x3;
  T.Mv[0] = T.n1a + T.n1b;
#pragma unroll
  for (int s = 1; s < 6; ++s)
    T.Mv[s] = __shfl(T.Mv[s - 1], 2 * l) + __shfl(T.Mv[s - 1], 2 * l + 1);
}
__device__ __forceinline__ float tile_sum4(const Tree& T) {
  return __shfl(T.Mv[5], 0) + __shfl(T.Mv[5], 1);
}
// Carry-seeded scan value for even in-tile prefix n (4l+2 / 4l+4); n=256 is
// the mid-scan / tile-sum value directly (caller substitutes).
__device__ __forceinline__ float fold4(const Tree& T, int n, float carry) {
  float acc = carry;
#pragma unroll
  for (int b = 7; b >= 2; --b) {
    float t = __shfl(T.Mv[b - 2], (n >> (b + 1)) << 1);
    acc = ((n >> b) & 1) ? acc + t : acc;
  }
  if (n & 2) acc = acc + T.n1a;
  return acc;
}

// ---------------- Kernel 1: tile sums (level-8) of rad ----------------
__global__ __launch_bounds__(256) void k_up1(const float* __restrict__ f0,
                                             float* __restrict__ gL,
                                             uint32_t ki0, uint32_t ki1) {
  int task = blockIdx.x * 4 + (threadIdx.x >> 6);
  int l = threadIdx.x & 63;
  int b = task / NTT, j = task - b * NTT;
  float4 f4 = *(const float4*)(f0 + (size_t)b * TT + j * TILE + 4 * l);
  const float RINV = 1.0f / 48000.0f;
  float rb0 = f4.x * RINV, rb1 = f4.y * RINV, rb2 = f4.z * RINV, rb3 = f4.w * RINV;
  bool ini = (j == 0) & (l == 0);
#pragma unroll
  for (int k = 0; k < DIM; ++k) {
    float h = (float)(k + 1);
    float r0 = fracf_(rb0 * h), r1 = fracf_(rb1 * h);
    float r2 = fracf_(rb2 * h), r3 = fracf_(rb3 * h);
    if (ini) r0 = r0 + rand_ini_val(ki0, ki1, b, k);
    Tree T; build_tree4(r0, r1, r2, r3, T, l);
    float ts = tile_sum4(T);
    if (l == 0) gL[(b * DIM + k) * NTT + j] = ts;
  }
}

// ---------------- Kernel 2/4: mid-scan (round-8 form: 36 blocks x 256) ------
// r8/r9 A/B showed the barrier version beats one-wave-per-row by ~10 us.
__global__ __launch_bounds__(256) void k_midscan(float* __restrict__ gbuf) {
  const int NLEV = 11;
  const int SZ[11]  = {1875, 937, 468, 234, 117, 58, 29, 14, 7, 3, 1};
  const int OFF[11] = {0, 1875, 2812, 3280, 3514, 3631, 3689, 3718, 3732, 3739, 3742};
  __shared__ float buf[3743];
  float* g = gbuf + (size_t)blockIdx.x * NTT;
  int tid = threadIdx.x;
  float tmp[8];
#pragma unroll
  for (int u = 0; u < 8; ++u) { int i = tid + u * 256; tmp[u] = (i < NTT) ? g[i] : 0.0f; }
#pragma unroll
  for (int u = 0; u < 8; ++u) { int i = tid + u * 256; if (i < NTT) buf[i] = tmp[u]; }
  __syncthreads();
#pragma unroll
  for (int lv = 0; lv + 1 < NLEV; ++lv) {            // up-sweep: pair reduce
    int m = SZ[lv + 1];
    const float* src = buf + OFF[lv];
    float* dst = buf + OFF[lv + 1];
    for (int i = tid; i < m; i += 256) dst[i] = src[2 * i] + src[2 * i + 1];
    __syncthreads();
  }
#pragma unroll
  for (int lv = NLEV - 2; lv >= 0; --lv) {           // down-sweep (in place)
    int n = SZ[lv], m = SZ[lv + 1];
    float* cur = buf + OFF[lv];
    const float* up = buf + OFF[lv + 1];
    for (int i = tid; i < m; i += 256) {
      float s = up[i];
      cur[2 * i + 1] = s;
      if (2 * i + 2 < n) cur[2 * i + 2] = s + cur[2 * i + 2];  // odd + elem order
    }
    __syncthreads();
  }
#pragma unroll
  for (int u = 0; u < 8; ++u) { int i = tid + u * 256; if (i < NTT) g[i] = buf[i]; }
}

// ---------------- Kernel 3: scan1 -> wraps + tile sums of y (+ Q0 carries) --
__global__ __launch_bounds__(256) void k_d1u2(const float* __restrict__ f0,
                                              const float* __restrict__ gS1,
                                              float* __restrict__ gL2,
                                              ulonglong2* __restrict__ wrapw,
                                              float* __restrict__ q0buf, int useq,
                                              uint32_t ki0, uint32_t ki1) {
  int task = blockIdx.x * 4 + (threadIdx.x >> 6);
  int l = threadIdx.x & 63;
  int b = task / NTT, j = task - b * NTT;
  float4 f4 = *(const float4*)(f0 + (size_t)b * TT + j * TILE + 4 * l);
  const float RINV = 1.0f / 48000.0f;
  float rb0 = f4.x * RINV, rb1 = f4.y * RINV, rb2 = f4.z * RINV, rb3 = f4.w * RINV;
  bool ini = (j == 0) & (l == 0);
  bool notfirst = (j > 0) | (l > 0);
#pragma unroll
  for (int k = 0; k < DIM; ++k) {
    float h = (float)(k + 1);
    float r0 = fracf_(rb0 * h), r1 = fracf_(rb1 * h);
    float r2 = fracf_(rb2 * h), r3 = fracf_(rb3 * h);
    if (ini) r0 = r0 + rand_ini_val(ki0, ki1, b, k);
    Tree T; build_tree4(r0, r1, r2, r3, T, l);
    int bju = __builtin_amdgcn_readfirstlane((b * DIM + k) * NTT + j);
    float S = gS1[bju];                        // scalar loads (uniform index)
    float C = (j > 0) ? gS1[bju - 1] : 0.0f;
    float c3 = fold4(T, 4 * l + 4, C);
    c3 = (l == 63) ? S : c3;
    float c1 = fold4(T, 4 * l + 2, C);
    float cp = __shfl_up(c3, 1);
    if (l == 0) cp = C;
    float c0 = cp + r0;                        // even positions: odd_prev + x
    float c2 = c1 + r2;
    float fp = fracf_(cp), g0 = fracf_(c0), g1 = fracf_(c1);
    float g2 = fracf_(c2), g3 = fracf_(c3);
    bool w0 = notfirst & (g0 < fp);
    bool w1 = g1 < g0;
    bool w2 = g2 < g1;
    bool w3 = g3 < g2;
    float y0 = w0 ? r0 - 1.0f : r0, y1 = w1 ? r1 - 1.0f : r1;
    float y2 = w2 ? r2 - 1.0f : r2, y3 = w3 ? r3 - 1.0f : r3;
    unsigned long long m0 = __ballot(w0), m1 = __ballot(w1);
    unsigned long long m2 = __ballot(w2), m3 = __ballot(w3);
    Tree Ty; build_tree4(y0, y1, y2, y3, Ty, l);
    float ts = tile_sum4(Ty);
    if (useq) {
      // zero-seeded per-lane in-tile carry of the y-scan (prefix 4l+4);
      // bracketing identical to the j==0 fold that validated in r3-r9.
      float q0 = (l == 63) ? ts : fold4(Ty, 4 * l + 4, 0.0f);
      q0buf[(size_t)bju * 64 + l] = q0;
    }
    if (l == 0) {
      gL2[bju] = ts;
      wrapw[2 * (size_t)bju]     = make_ulonglong2(m0, m1);
      wrapw[2 * (size_t)bju + 1] = make_ulonglong2(m2, m3);
    }
  }
}

// ---------------- Kernel 5a: Q0 path — no tree rebuild at all ---------------
__global__ __launch_bounds__(256) void k_d2out_q(const float* __restrict__ f0,
                                                 const float* __restrict__ gS2,
                                                 const ulonglong2* __restrict__ wrapw,
                                                 const float* __restrict__ q0buf,
                                                 float* __restrict__ out,
                                                 uint32_t ki0, uint32_t ki1,
                                                 uint32_t kn0, uint32_t kn1) {
  __shared__ float sb[4][64 * 37];             // 37,888 B; stride 37 -> no conflicts
  int w = threadIdx.x >> 6, l = threadIdx.x & 63;
  int task = blockIdx.x * 4 + w;
  int b = task / NTT, j = task - b * NTT;
  int t0 = j * TILE + 4 * l;
  float4 f4 = *(const float4*)(f0 + (size_t)b * TT + t0);
  const float RINV = 1.0f / 48000.0f;
  float rb0 = f4.x * RINV, rb1 = f4.y * RINV, rb2 = f4.z * RINV;
  bool ini = (j == 0) & (l == 0);
  float uv0 = (f4.x > 0.0f) ? 1.0f : 0.0f, uv1 = (f4.y > 0.0f) ? 1.0f : 0.0f;
  float uv2 = (f4.z > 0.0f) ? 1.0f : 0.0f, uv3 = (f4.w > 0.0f) ? 1.0f : 0.0f;
  const float AMP3 = 0.0333333333333333333f;   // f32(0.1/3)
  float na0 = uv0 * 0.003f + (1.0f - uv0) * AMP3;
  float na1 = uv1 * 0.003f + (1.0f - uv1) * AMP3;
  float na2 = uv2 * 0.003f + (1.0f - uv2) * AMP3;
  float na3 = uv3 * 0.003f + (1.0f - uv3) * AMP3;
  float* sl = sb[w];
  int sbase = l * 37;
#pragma unroll
  for (int k = 0; k < DIM; ++k) {
    float h = (float)(k + 1);
    float r0 = fracf_(rb0 * h), r1 = fracf_(rb1 * h), r2 = fracf_(rb2 * h);
    if (ini) r0 = r0 + rand_ini_val(ki0, ki1, b, k);
    int bju = __builtin_amdgcn_readfirstlane((b * DIM + k) * NTT + j);
    ulonglong2 wA = wrapw[2 * (size_t)bju];
    unsigned long long wBx = wrapw[2 * (size_t)bju + 1].x;
    float C2 = (j > 0) ? gS2[bju - 1] : 0.0f;
    float qv = q0buf[(size_t)bju * 64 + l];    // in-tile lane carry (prefix 4l+4)
    float qp = __shfl_up(qv, 1);
    if (l == 0) qp = 0.0f;
    float y0 = selbit(wA.x, r0, r0 - 1.0f);
    float y1 = selbit(wA.y, r1, r1 - 1.0f);
    float y2 = selbit(wBx, r2, r2 - 1.0f);
    // d values: (C2 + Q0) re-association differs from the carry-seeded fold by
    // <= few ulp at |.|<=4 (~1e-6); d feeds ONLY sin (no comparisons) -> safe.
    float base = C2 + qp;
    float d0 = base + y0;
    float d1 = base + (y0 + y1);
    float d2 = d1 + y2;
    float d3 = C2 + qv;
    float s0 = __builtin_amdgcn_sinf(d0) * 0.1f;   // v_sin: revolutions
    float s1 = __builtin_amdgcn_sinf(d1) * 0.1f;
    float s2 = __builtin_amdgcn_sinf(d2) * 0.1f;
    float s3 = __builtin_amdgcn_sinf(d3) * 0.1f;
    uint32_t fi = (uint32_t)(b * TT + t0) * (uint32_t)DIM + (uint32_t)k;
    float n0 = nrm_(noise_bits(kn0, kn1, fi));
    float n1 = nrm_(noise_bits(kn0, kn1, fi + 9u));
    float n2 = nrm_(noise_bits(kn0, kn1, fi + 18u));
    float n3 = nrm_(noise_bits(kn0, kn1, fi + 27u));
    sl[sbase + k]      = s0 * uv0 + na0 * n0;
    sl[sbase + 9 + k]  = s1 * uv1 + na1 * n1;
    sl[sbase + 18 + k] = s2 * uv2 + na2 * n2;
    sl[sbase + 27 + k] = s3 * uv3 + na3 * n3;
  }
  float4* po = (float4*)(out + ((size_t)b * TT + (size_t)j * TILE) * DIM);
#pragma unroll
  for (int q = 0; q < 9; ++q) {
    int gg = (q * 64 + l) * 4;
    int a = gg + gg / 36;
    po[q * 64 + l] = make_float4(sl[a], sl[a + 1], sl[a + 2], sl[a + 3]);
  }
}

// ---------------- Kernel 5b: fallback (r9 tree version) if ws too small -----
__global__ __launch_bounds__(256) void k_d2out(const float* __restrict__ f0,
                                               const float* __restrict__ gS2,
                                               const ulonglong2* __restrict__ wrapw,
                                               float* __restrict__ out,
                                               uint32_t ki0, uint32_t ki1,
                                               uint32_t kn0, uint32_t kn1) {
  __shared__ float sb[4][64 * 37];
  int w = threadIdx.x >> 6, l = threadIdx.x & 63;
  int task = blockIdx.x * 4 + w;
  int b = task / NTT, j = task - b * NTT;
  int t0 = j * TILE + 4 * l;
  float4 f4 = *(const float4*)(f0 + (size_t)b * TT + t0);
  const float RINV = 1.0f / 48000.0f;
  float rb0 = f4.x * RINV, rb1 = f4.y * RINV, rb2 = f4.z * RINV, rb3 = f4.w * RINV;
  bool ini = (j == 0) & (l == 0);
  float uv0 = (f4.x > 0.0f) ? 1.0f : 0.0f, uv1 = (f4.y > 0.0f) ? 1.0f : 0.0f;
  float uv2 = (f4.z > 0.0f) ? 1.0f : 0.0f, uv3 = (f4.w > 0.0f) ? 1.0f : 0.0f;
  const float AMP3 = 0.0333333333333333333f;
  float na0 = uv0 * 0.003f + (1.0f - uv0) * AMP3;
  float na1 = uv1 * 0.003f + (1.0f - uv1) * AMP3;
  float na2 = uv2 * 0.003f + (1.0f - uv2) * AMP3;
  float na3 = uv3 * 0.003f + (1.0f - uv3) * AMP3;
  float* sl = sb[w];
  int sbase = l * 37;
#pragma unroll
  for (int k = 0; k < DIM; ++k) {
    float h = (float)(k + 1);
    float r0 = fracf_(rb0 * h), r1 = fracf_(rb1 * h);
    float r2 = fracf_(rb2 * h), r3 = fracf_(rb3 * h);
    if (ini) r0 = r0 + rand_ini_val(ki0, ki1, b, k);
    int bju = __builtin_amdgcn_readfirstlane((b * DIM + k) * NTT + j);
    ulonglong2 wA = wrapw[2 * (size_t)bju];
    ulonglong2 wB = wrapw[2 * (size_t)bju + 1];
    float S2 = gS2[bju];
    float C2 = (j > 0) ? gS2[bju - 1] : 0.0f;
    float y0 = selbit(wA.x, r0, r0 - 1.0f);
    float y1 = selbit(wA.y, r1, r1 - 1.0f);
    float y2 = selbit(wB.x, r2, r2 - 1.0f);
    float y3 = selbit(wB.y, r3, r3 - 1.0f);
    Tree T; build_tree4(y0, y1, y2, y3, T, l);
    float d3 = fold4(T, 4 * l + 4, C2);
    d3 = (l == 63) ? S2 : d3;
    float d1 = fold4(T, 4 * l + 2, C2);
    float dp = __shfl_up(d3, 1);
    if (l == 0) dp = C2;
    float d0 = dp + y0;
    float d2 = d1 + y2;
    float s0 = __builtin_amdgcn_sinf(d0) * 0.1f;
    float s1 = __builtin_amdgcn_sinf(d1) * 0.1f;
    float s2 = __builtin_amdgcn_sinf(d2) * 0.1f;
    float s3 = __builtin_amdgcn_sinf(d3) * 0.1f;
    uint32_t fi = (uint32_t)(b * TT + t0) * (uint32_t)DIM + (uint32_t)k;
    float n0 = nrm_(noise_bits(kn0, kn1, fi));
    float n1 = nrm_(noise_bits(kn0, kn1, fi + 9u));
    float n2 = nrm_(noise_bits(kn0, kn1, fi + 18u));
    float n3 = nrm_(noise_bits(kn0, kn1, fi + 27u));
    sl[sbase + k]      = s0 * uv0 + na0 * n0;
    sl[sbase + 9 + k]  = s1 * uv1 + na1 * n1;
    sl[sbase + 18 + k] = s2 * uv2 + na2 * n2;
    sl[sbase + 27 + k] = s3 * uv3 + na3 * n3;
  }
  float4* po = (float4*)(out + ((size_t)b * TT + (size_t)j * TILE) * DIM);
#pragma unroll
  for (int q = 0; q < 9; ++q) {
    int gg = (q * 64 + l) * 4;
    int a = gg + gg / 36;
    po[q * 64 + l] = make_float4(sl[a], sl[a + 1], sl[a + 2], sl[a + 3]);
  }
}

extern "C" void kernel_launch(void* const* d_in, const int* in_sizes, int n_in,
                              void* d_out, int out_size, void* d_ws, size_t ws_size,
                              hipStream_t stream) {
  (void)in_sizes; (void)n_in; (void)out_size;
  const float* f0 = (const float*)d_in[0];
  float* out = (float*)d_out;
  const size_t LANES = (size_t)BB * DIM;                 // 36
  float* gBuf1 = (float*)d_ws;                           // 36*1875 f32
  float* gBuf2 = gBuf1 + LANES * NTT;                    // 36*1875 f32
  ulonglong2* wrapw =
      (ulonglong2*)((char*)d_ws + 2 * LANES * NTT * sizeof(float));      // 2.16 MB
  size_t baseBytes = 2 * LANES * NTT * sizeof(float) + LANES * NTT * 32; // ~2.7 MB
  size_t qBytes = LANES * NTT * 64 * sizeof(float);                     // 17.28 MB
  float* q0buf = (float*)((char*)d_ws + baseBytes);
  int useq = (ws_size >= baseBytes + qBytes) ? 1 : 0;

  uint32_t ki0, ki1, kn0, kn1;
#if PARTITIONABLE
  threefry2x32(0u, 42u, 0u, 0u, ki0, ki1);   // k_ini   = split(key(42))[0]
  threefry2x32(0u, 42u, 0u, 1u, kn0, kn1);   // k_noise = split(key(42))[1]
#else
  uint32_t a0, a1, b0, b1;
  threefry2x32(0u, 42u, 0u, 2u, a0, a1);
  threefry2x32(0u, 42u, 1u, 3u, b0, b1);
  ki0 = a0; ki1 = b0;
  kn0 = a1; kn1 = b1;
#endif

  k_up1    <<<(BB * NTT) / 4, 256, 0, stream>>>(f0, gBuf1, ki0, ki1);
  k_midscan<<<36, 256, 0, stream>>>(gBuf1);
  k_d1u2   <<<(BB * NTT) / 4, 256, 0, stream>>>(f0, gBuf1, gBuf2, wrapw,
                                                q0buf, useq, ki0, ki1);
  k_midscan<<<36, 256, 0, stream>>>(gBuf2);
  if (useq)
    k_d2out_q<<<(BB * NTT) / 4, 256, 0, stream>>>(f0, gBuf2, wrapw, q0buf, out,
                                                  ki0, ki1, kn0, kn1);
  else
    k_d2out  <<<(BB * NTT) / 4, 256, 0, stream>>>(f0, gBuf2, wrapw, out,
                                                  ki0, ki1, kn0, kn1);
}